// Round 12
// baseline (596.357 us; speedup 1.0000x reference)
//
#include <hip/hip_runtime.h>
#include <math.h>

// ---------------------------------------------------------------------------
// VQ-VAE forward. bf16 MFMA implicit-GEMM.
// rconv_k v2: 512 thr = 8 waves (2M x 4N), full-K wave tile 32x64; 80KB LDS
// (2 x 40KB staging bufs) -> 2 blocks/CU for inter-block latency hiding.
// No kg-split -> no merge. Fused residual-1x1 phase2 overlays retired LDS.
// ---------------------------------------------------------------------------

typedef __attribute__((ext_vector_type(8))) short bf16x8;
typedef __attribute__((ext_vector_type(4))) float f32x4;

__device__ __forceinline__ float bf2f(short s) {
    unsigned u = ((unsigned)(unsigned short)s) << 16;
    return __builtin_bit_cast(float, u);
}
__device__ __forceinline__ unsigned short f2bfu(float f) {
    unsigned u = __builtin_bit_cast(unsigned, f);
    u = (u + 0x7fff + ((u >> 16) & 1)) >> 16;
    return (unsigned short)u;
}
__device__ __forceinline__ short f2bf(float f) { return (short)f2bfu(f); }
__device__ __forceinline__ int pack2(float a, float b) {
    return (int)f2bfu(a) | ((int)f2bfu(b) << 16);
}

template<int ACT>
__device__ __forceinline__ float actf(float v) {
    if (ACT == 1) return fmaxf(v, 0.f);
    if (ACT == 2) return v > 0.f ? v : 0.01f * v;
    return v;
}

__device__ __forceinline__ void gload_lds16(const void* g, void* l) {
    __builtin_amdgcn_global_load_lds(
        (const __attribute__((address_space(1))) unsigned int*)g,
        (__attribute__((address_space(3))) unsigned int*)l, 16, 0, 0);
}

__device__ __forceinline__ int fof(int r) { return (r & 3) ^ ((r >> 2) & 3); }

#define WAITV(N) asm volatile("s_waitcnt vmcnt(" #N ")" ::: "memory")
#define LGKM0 asm volatile("s_waitcnt lgkmcnt(0)" ::: "memory")

// ---------- weight prep: LDS-tiled transpose (coalesced both sides) --------
__device__ __forceinline__ void prep_t(const float* __restrict__ src,
        short* __restrict__ dst, int COUT, int CIN, int T, int TP,
        int blk, float* sT, int tid) {
    int opc = COUT >> 2;
    int c = blk / opc, oc0 = (blk - c * opc) * 4;
    const float* s = src + ((size_t)c * COUT + oc0) * CIN * T;
    int n = 4 * CIN * T;
    for (int i = tid; i < n; i += 256) {
        int ocl = i / (CIN * T); int rem = i - ocl * (CIN * T);
        int ic = rem / T, t = rem - ic * T;
        sT[(ocl * CIN + ic) * TP + t] = s[i];
    }
    __syncthreads();
    for (int i = tid; i < n; i += 256) {
        int t = i / (4 * CIN); int rem = i - t * (4 * CIN);
        int ocl = rem / CIN, ic = rem - ocl * CIN;
        dst[(((size_t)c * T + t) * COUT + oc0 + ocl) * CIN + ic]
            = f2bf(sT[(ocl * CIN + ic) * TP + t]);
    }
    __syncthreads();
}

__global__ __launch_bounds__(256) void prep_all_k(
        const float* ew1, const float* ew2, const float* erw3,
        const float* erw1, const float* ew3, const float* dw0,
        const float* drw3, const float* drw1, const float* tw0,
        short* Wp1, short* We2, short* Wer3, short* We11, short* Wz,
        short* Wd0, short* Wdr3, short* Wdr1, short* Wt0) {
    __shared__ float sT[9216];
    int bid = blockIdx.x, tid = threadIdx.x;
    if (bid < 64)        prep_t(ew1, Wp1, 256, 128, 16, 17, bid, sT, tid);
    else if (bid < 128)  prep_t(ew2, We2, 256, 256, 9, 9, bid - 64, sT, tid);
    else if (bid < 512)  prep_t(erw3, Wer3, 256, 256, 9, 9, bid - 128, sT, tid);
    else if (bid < 896)  prep_t(erw1, We11, 256, 256, 1, 1, bid - 512, sT, tid);
    else if (bid < 912)  prep_t(ew3, Wz, 64, 256, 1, 1, bid - 896, sT, tid);
    else if (bid < 976)  prep_t(dw0, Wd0, 256, 64, 9, 9, bid - 912, sT, tid);
    else if (bid < 1360) prep_t(drw3, Wdr3, 256, 256, 9, 9, bid - 976, sT, tid);
    else if (bid < 1744) prep_t(drw1, Wdr1, 256, 256, 1, 1, bid - 1360, sT, tid);
    else {
        int i = (bid - 1744) * 256 + tid;
        if (i < 524288) {
            int ic = i & 255; int r = i >> 8;
            int oc = r & 127; r >>= 7;
            int tap = r & 3; int par = r >> 2;
            int py = par >> 1, px = par & 1, my = tap >> 1, mx = tap & 1;
            int ky = 2 * my + (py ^ 1), kx = 2 * mx + (px ^ 1);
            Wt0[i] = f2bf(tw0[(((size_t)ic * 128 + oc) * 4 + ky) * 4 + kx]);
        }
    }
}

// ------------------ halo zero (all 4 buffers, one dispatch) ----------------
__global__ __launch_bounds__(256) void halo_all_k(short* P0, short* PB,
        short* PC, short* Pq) {
    int g = blockIdx.x * 256 + threadIdx.x;
    short* base; int W, C, idx;
    if (g < 135168)      { base = P0; W = 68; C = 128; idx = g; }
    else if (g < 274432) { base = PB; W = 36; C = 256; idx = g - 135168; }
    else if (g < 413696) { base = PC; W = 36; C = 256; idx = g - 274432; }
    else                 { base = Pq; W = 36; C = 64;  idx = g - 413696; }
    int c8 = C >> 3;
    int per_img = (4 * W + (W - 4) * 4) * c8;
    int img = idx / per_img, r = idx - img * per_img;
    int row, off;
    if (r < 4 * W * c8) {
        int rr = r / (W * c8);
        row = (rr < 2) ? rr : W - 4 + rr;
        off = r - rr * (W * c8);
    } else {
        int r2 = r - 4 * W * c8;
        row = 2 + r2 / (4 * c8);
        int q = r2 - (row - 2) * (4 * c8);
        off = (q < 2 * c8) ? q : (W - 2) * c8 + (q - 2 * c8);
    }
    ((int4*)(base + ((size_t)img * W + row) * W * C))[off] = int4{0, 0, 0, 0};
}

// ---------- rconv v2: 8-wave BM=64 BN=256, full-K waves, 2 blocks/CU -------
template<int CIN, int NTAPS, int TAPPAT, int SM, int INW, int OUTACT,
         bool HASB, bool FUSE>
__global__ __launch_bounds__(512, 4) void rconv_k(
        const short* __restrict__ in, const short* __restrict__ Wp,
        const float* __restrict__ bias, const short* __restrict__ W1p,
        short* __restrict__ outp) {
    constexpr int CH64 = (CIN >= 128) ? CIN / 64 : 1;
    constexpr int LG2 = (CH64 == 4) ? 2 : (CH64 == 2) ? 1 : 0;
    constexpr int ST = NTAPS * CH64;
    __shared__ short sLds[40960];     // 80KB: 2 bufs x (A 8KB + B 32KB)
    const int tid = threadIdx.x;
    const int lane = tid & 63, wv = tid >> 6;
    const int wc = wv & 3, mh = wv >> 2;     // 4 N-quarters x 2 M-halves
    const int pix0 = blockIdx.x * 64;
    const int l15 = lane & 15, hi = lane >> 4;
    const int sl = hi ^ fof(l15);

    // ---- A staging source (pre-swizzled) ----
    const int arow = tid >> 3, aslot = tid & 7;
    const short* Aptr;
    {
        int pixa = pix0 + arow;
        int ba = pixa >> 10, Ya = (pixa >> 5) & 31, Xa = pixa & 31;
        Aptr = in + (size_t)((ba * INW + SM * Ya + 2) * INW + (SM * Xa + 2)) * CIN
             + (aslot >> 2) * 32 + (((aslot & 3) ^ fof(arow)) * 8);
    }
    // ---- B staging sources (4 x 16B / thread) ----
    const short* Bptr[4];
#pragma unroll
    for (int j = 0; j < 4; j++) {
        int gb = tid + 512 * j;
        int kkb = gb >> 10, oc = (gb >> 2) & 255, slb = gb & 3;
        Bptr[j] = Wp + (size_t)oc * CIN + kkb * 32 + ((slb ^ fof(oc)) * 8);
    }

    auto stage = [&](int s, int bi) {
        int t = s >> LG2;
        int c0 = (s & (CH64 - 1)) * 64;
        int rof, cof;
        if (TAPPAT == 1) { rof = t / 3 - 1; cof = t % 3 - 1; }
        else             { rof = (t >> 2) - 1; cof = (t & 3) - 1; }
        char* L = (char*)sLds + bi * 40960;   // byte offset
        gload_lds16(Aptr + (rof * INW + cof) * CIN + c0, L + tid * 16);
        int woff = t * (256 * CIN) + c0;
#pragma unroll
        for (int j = 0; j < 4; j++)
            gload_lds16(Bptr[j] + woff, L + 8192 + (tid + 512 * j) * 16);
    };

    f32x4 acc[2][4];
#pragma unroll
    for (int mi = 0; mi < 2; mi++)
#pragma unroll
        for (int ni = 0; ni < 4; ni++) acc[mi][ni] = f32x4{0.f, 0.f, 0.f, 0.f};

    stage(0, 0);
    for (int s = 0; s < ST; ++s) {
        WAITV(0);
        __builtin_amdgcn_s_barrier();
        if (s + 1 < ST) stage(s + 1, (s + 1) & 1);
        const char* L = (const char*)sLds + (s & 1) * 40960;
        bf16x8 af[2][2], bfr[4][2];
#pragma unroll
        for (int kk = 0; kk < 2; kk++) {
#pragma unroll
            for (int mi = 0; mi < 2; mi++)
                af[mi][kk] = *(const bf16x8*)(L
                    + (mh * 32 + mi * 16 + l15) * 128 + kk * 64 + sl * 16);
#pragma unroll
            for (int ni = 0; ni < 4; ni++)
                bfr[ni][kk] = *(const bf16x8*)(L + 8192 + kk * 16384
                    + (wc * 64 + ni * 16 + l15) * 64 + sl * 16);
        }
        __builtin_amdgcn_s_setprio(1);
#pragma unroll
        for (int kk = 0; kk < 2; kk++)
#pragma unroll
            for (int mi = 0; mi < 2; mi++)
#pragma unroll
                for (int ni = 0; ni < 4; ni++)
                    acc[mi][ni] = __builtin_amdgcn_mfma_f32_16x16x32_bf16(
                        af[mi][kk], bfr[ni][kk], acc[mi][ni], 0, 0, 0);
        __builtin_amdgcn_s_setprio(0);
    }

    if (!FUSE) {
        __syncthreads();                       // staging reads done everywhere
        float* MB = (float*)sLds;              // 64KB [row64][col256] f32
#pragma unroll
        for (int mi = 0; mi < 2; mi++)
#pragma unroll
            for (int ni = 0; ni < 4; ni++) {
                int col = wc * 64 + ni * 16 + l15;
                float b = HASB ? bias[col] : 0.f;
#pragma unroll
                for (int r = 0; r < 4; r++)
                    MB[(mh * 32 + mi * 16 + hi * 4 + r) * 256 + col]
                        = acc[mi][ni][r] + b;
            }
        __syncthreads();
#pragma unroll
        for (int j = 0; j < 4; j++) {
            int idx = j * 512 + tid;
            int p = idx >> 5, c0 = (idx & 31) * 8;
            int pix = pix0 + p;
            int b = pix >> 10, Y = (pix >> 5) & 31, X = pix & 31;
            size_t base = (((size_t)b * 36 + Y + 2) * 36 + X + 2) * 256 + c0;
            const float4* m4 = (const float4*)(MB + p * 256 + c0);
            float4 lo = m4[0], hv = m4[1];
            int pk[4];
            pk[0] = pack2(actf<OUTACT>(lo.x), actf<OUTACT>(lo.y));
            pk[1] = pack2(actf<OUTACT>(lo.z), actf<OUTACT>(lo.w));
            pk[2] = pack2(actf<OUTACT>(hv.x), actf<OUTACT>(hv.y));
            pk[3] = pack2(actf<OUTACT>(hv.z), actf<OUTACT>(hv.w));
            *(int4*)(outp + base) = *(int4*)pk;
        }
        return;
    }

    // ---------------- FUSE: relu(acc) -> H; 1x1 via staged W1 ---------------
    short* H = sLds;                           // 32KB [grp8][row64][32]
    __syncthreads();                           // staging reads done
#pragma unroll
    for (int mi = 0; mi < 2; mi++)
#pragma unroll
        for (int ni = 0; ni < 4; ni++) {
            int col = wc * 64 + ni * 16 + l15;
#pragma unroll
            for (int r = 0; r < 4; r++) {
                int row = mh * 32 + mi * 16 + hi * 4 + r;
                H[((col >> 5) * 64 + row) * 32
                  + (((col >> 3) & 3) ^ fof(row)) * 8 + (col & 7)]
                    = f2bf(fmaxf(acc[mi][ni][r], 0.f));
            }
        }
    // W1 staging: chunks of K=32 (16KB), double-buffered @ bytes 32768/49152
    const short* W1ptr[2];
#pragma unroll
    for (int j = 0; j < 2; j++) {
        int gb = tid + 512 * j;
        int oc = gb >> 2, slb = gb & 3;
        W1ptr[j] = W1p + (size_t)oc * 256 + ((slb ^ fof(oc)) * 8);
    }
    auto stage2 = [&](int c) {
        char* L = (char*)sLds + 32768 + (c & 1) * 16384;
        gload_lds16(W1ptr[0] + c * 32, L + tid * 16);
        gload_lds16(W1ptr[1] + c * 32, L + (tid + 512) * 16);
    };
    LGKM0;
    __builtin_amdgcn_sched_barrier(0);
    __syncthreads();                           // H visible to all waves
    stage2(0);
    stage2(1);

    f32x4 acc2[2][4];
#pragma unroll
    for (int mi = 0; mi < 2; mi++)
#pragma unroll
        for (int ni = 0; ni < 4; ni++) acc2[mi][ni] = f32x4{0.f, 0.f, 0.f, 0.f};

    for (int c = 0; c < 8; ++c) {
        if (c < 7) { WAITV(2); } else { WAITV(0); }
        __builtin_amdgcn_s_barrier();
        const char* LW = (const char*)sLds + 32768 + (c & 1) * 16384;
        bf16x8 af2[2], bf2r[4];
#pragma unroll
        for (int mi = 0; mi < 2; mi++) {
            int row = mh * 32 + mi * 16 + l15;
            af2[mi] = *(const bf16x8*)&H[(c * 64 + row) * 32 + sl * 8];
        }
#pragma unroll
        for (int ni = 0; ni < 4; ni++)
            bf2r[ni] = *(const bf16x8*)(LW
                + (wc * 64 + ni * 16 + l15) * 64 + sl * 16);
        LGKM0;
        __builtin_amdgcn_sched_barrier(0);
        __builtin_amdgcn_s_barrier();          // all reads of this W1 buf done
        if (c < 6) stage2(c + 2);
        __builtin_amdgcn_s_setprio(1);
#pragma unroll
        for (int mi = 0; mi < 2; mi++)
#pragma unroll
            for (int ni = 0; ni < 4; ni++)
                acc2[mi][ni] = __builtin_amdgcn_mfma_f32_16x16x32_bf16(
                    af2[mi], bf2r[ni], acc2[mi][ni], 0, 0, 0);
        __builtin_amdgcn_s_setprio(0);
    }

    __syncthreads();                           // phase-2 LDS reads done
    float* MB = (float*)sLds;                  // 64KB f32 bounce
#pragma unroll
    for (int mi = 0; mi < 2; mi++)
#pragma unroll
        for (int ni = 0; ni < 4; ni++) {
            int col = wc * 64 + ni * 16 + l15;
#pragma unroll
            for (int r = 0; r < 4; r++)
                MB[(mh * 32 + mi * 16 + hi * 4 + r) * 256 + col]
                    = acc2[mi][ni][r];
        }
    __syncthreads();
#pragma unroll
    for (int j = 0; j < 4; j++) {
        int idx = j * 512 + tid;
        int p = idx >> 5, c0 = (idx & 31) * 8;
        int pix = pix0 + p;
        int b = pix >> 10, Y = (pix >> 5) & 31, X = pix & 31;
        size_t base = (((size_t)b * 36 + Y + 2) * 36 + X + 2) * 256 + c0;
        const float4* m4 = (const float4*)(MB + p * 256 + c0);
        float4 lo = m4[0], hv = m4[1];
        bf16x8 rv = *(const bf16x8*)(in + base);
        int pk[4];
        pk[0] = pack2(actf<OUTACT>(lo.x + bf2f(rv[0])),
                      actf<OUTACT>(lo.y + bf2f(rv[1])));
        pk[1] = pack2(actf<OUTACT>(lo.z + bf2f(rv[2])),
                      actf<OUTACT>(lo.w + bf2f(rv[3])));
        pk[2] = pack2(actf<OUTACT>(hv.x + bf2f(rv[4])),
                      actf<OUTACT>(hv.y + bf2f(rv[5])));
        pk[3] = pack2(actf<OUTACT>(hv.z + bf2f(rv[6])),
                      actf<OUTACT>(hv.w + bf2f(rv[7])));
        *(int4*)(outp + base) = *(int4*)pk;
    }
}

// ------------------- 4-wave gconv (tw0 parities, ew3) ----------------------
template<int CIN, int COUT, int NTAPS, int TAPPAT, int SM, int INW,
         int OUTACT, bool RES, bool HASB, int OUTMODE, int BN>
__global__ __launch_bounds__(256) void gconv_k(
        const short* __restrict__ in, const short* __restrict__ Wp,
        const float* __restrict__ bias, const short* __restrict__ res,
        void* __restrict__ outp) {
    constexpr int KCH = CIN / 32;
    constexpr int LG = (KCH == 8) ? 3 : (KCH == 4) ? 2 : (KCH == 2) ? 1 : 0;
    constexpr int ST = NTAPS * KCH;
    constexpr int NF = BN / 32;
    constexpr int WN = BN / 2;
    __shared__ short sA[3 * 128 * 32];
    __shared__ short sB[3 * BN * 32];
    const int tid = threadIdx.x;
    const int lane = tid & 63, wv = tid >> 6;
    const int wr = wv >> 1, wc = wv & 1;
    const int pix0 = blockIdx.x * 128;
    const int oc0 = blockIdx.y * BN;
    int py = 0, px = 0;
    if (TAPPAT == 3) {
        int par = blockIdx.z;
        py = par >> 1; px = par & 1;
        Wp += (size_t)par * NTAPS * COUT * CIN;
    }
    const int sp = tid >> 2;
    const int swz = ((tid & 3) ^ fof(sp)) * 8;
    int rbA[2];
#pragma unroll
    for (int rd = 0; rd < 2; rd++) {
        int pix = pix0 + sp + rd * 64;
        int b = pix >> 10, Y = (pix >> 5) & 31, X = pix & 31;
        rbA[rd] = ((b * INW + SM * Y + 2) * INW + (SM * X + 2)) * CIN + swz;
    }
    const int wb0 = (oc0 + sp) * CIN + swz;
    const int wb1 = (oc0 + sp + 64) * CIN + swz;

    f32x4 acc[4][NF];
#pragma unroll
    for (int i = 0; i < 4; i++)
#pragma unroll
        for (int j = 0; j < NF; j++) acc[i][j] = f32x4{0.f, 0.f, 0.f, 0.f};

    const int sslot = ((lane >> 4) ^ fof(lane & 15)) * 8;
    const int abase = (wr * 64 + (lane & 15)) * 32 + sslot;
    const int bbase = (wc * WN + (lane & 15)) * 32 + sslot;

    auto stage = [&](int s, int biq) {
        int t = s >> LG, c = s & (KCH - 1);
        int rof, cof;
        if (TAPPAT == 0) { rof = 0; cof = 0; }
        else if (TAPPAT == 1) { rof = t / 3 - 1; cof = t % 3 - 1; }
        else if (TAPPAT == 2) { rof = t / 4 - 1; cof = t % 4 - 1; }
        else { int my = t >> 1, mx = t & 1;
               rof = (py == 0) ? -my : 1 - my;
               cof = (px == 0) ? -mx : 1 - mx; }
        const int tapoff = (rof * INW + cof) * CIN + c * 32;
        char* a = (char*)sA + biq * 8192;
        char* b = (char*)sB + biq * (BN * 64);
        const short* wt = Wp + (size_t)t * COUT * CIN + c * 32;
        gload_lds16(in + rbA[0] + tapoff, a + tid * 16);
        gload_lds16(in + rbA[1] + tapoff, a + 4096 + tid * 16);
        gload_lds16(wt + wb0, b + tid * 16);
        if (BN == 128) gload_lds16(wt + wb1, b + 4096 + tid * 16);
    };

    stage(0, 0);
    stage(1, 1);
    int cur = 0;
    for (int s = 0; s < ST; ++s) {
        if (s < ST - 1) {
            if (BN == 128) { WAITV(4); } else { WAITV(3); }
        } else {
            WAITV(0);
        }
        __builtin_amdgcn_s_barrier();
        int nxt = cur + 2; if (nxt >= 3) nxt -= 3;
        if (s + 2 < ST) stage(s + 2, nxt);
        const short* a = sA + cur * 4096;
        const short* b = sB + cur * (BN * 32);
        bf16x8 af[4], bfm[NF];
#pragma unroll
        for (int mi = 0; mi < 4; mi++)
            af[mi] = *(const bf16x8*)(a + abase + mi * 512);
#pragma unroll
        for (int ni = 0; ni < NF; ni++)
            bfm[ni] = *(const bf16x8*)(b + bbase + ni * 512);
        __builtin_amdgcn_s_setprio(1);
#pragma unroll
        for (int mi = 0; mi < 4; mi++)
#pragma unroll
            for (int ni = 0; ni < NF; ni++)
                acc[mi][ni] = __builtin_amdgcn_mfma_f32_16x16x32_bf16(
                    af[mi], bfm[ni], acc[mi][ni], 0, 0, 0);
        __builtin_amdgcn_s_setprio(0);
        cur = (cur == 2) ? 0 : cur + 1;
    }
#pragma unroll
    for (int mi = 0; mi < 4; mi++) {
#pragma unroll
        for (int r = 0; r < 4; r++) {
            int pix = pix0 + wr * 64 + mi * 16 + (lane >> 4) * 4 + r;
            int b = pix >> 10, Y = (pix >> 5) & 31, X = pix & 31;
            size_t rowoff = 0;
            if (OUTMODE == 0)
                rowoff = (((size_t)b * 36 + Y + 2) * 36 + X + 2) * COUT;
            else if (OUTMODE == 2)
                rowoff = (((size_t)b * 68 + 2 * Y + py + 2) * 68 + 2 * X + px + 2) * 128;
#pragma unroll
            for (int ni = 0; ni < NF; ni++) {
                int col = oc0 + wc * WN + ni * 16 + (lane & 15);
                float v = acc[mi][ni][r];
                if (HASB) v += bias[col];
                if (OUTMODE == 1) {
                    ((float*)outp)[(size_t)pix * COUT + col] = actf<OUTACT>(v);
                } else {
                    size_t off = rowoff + col;
                    if (RES) v += bf2f(res[off]);
                    ((short*)outp)[off] = f2bf(actf<OUTACT>(v));
                }
            }
        }
    }
}

// --------------- conv0: 4x4 s2 p1, Cin=3, MFMA implicit GEMM ---------------
__global__ __launch_bounds__(256) void conv0_k(const float* __restrict__ x,
        const float* __restrict__ W, const float* __restrict__ bias,
        short* __restrict__ P0) {
    __shared__ float sP[3 * 4 * 132];
    __shared__ short sB[8192];
    __shared__ float sMB[8192];
    int y = blockIdx.x, b = blockIdx.y;
    int tid = threadIdx.x;
    int lane = tid & 63, w = tid >> 6;
    int l15 = lane & 15, hi = lane >> 4;
    int sl = hi ^ fof(l15);
    for (int t = tid; t < 8192; t += 256) {
        int oc = t >> 6, k = t & 63;
        float v = (k < 48) ? W[(size_t)oc * 48 + k] : 0.f;
        int kk = k >> 5, slot = (k >> 3) & 3, j = k & 7;
        sB[oc * 64 + kk * 32 + ((slot ^ fof(oc)) * 8) + j] = f2bf(v);
    }
    for (int t = tid; t < 1560; t += 256) {
        int ic = t / 520; int r = t - ic * 520;
        int ry = r / 130, rx = r - ry * 130;
        int iy = 2 * y - 1 + ry, ix = rx - 1;
        float v = 0.f;
        if ((unsigned)iy < 128u && (unsigned)ix < 128u)
            v = x[((size_t)b * 3 + ic) * 16384 + iy * 128 + ix];
        sP[(ic * 4 + ry) * 132 + rx] = v;
    }
    __syncthreads();
    int ox = w * 16 + l15;
    bf16x8 af[2];
#pragma unroll
    for (int kk = 0; kk < 2; kk++) {
        short tmp[8];
#pragma unroll
        for (int j = 0; j < 8; j++) {
            int k = kk * 32 + hi * 8 + j;
            float v = 0.f;
            if (k < 48) {
                int ic = k >> 4, ky = (k >> 2) & 3, kx = k & 3;
                v = sP[(ic * 4 + ky) * 132 + 2 * ox + kx];
            }
            tmp[j] = f2bf(v);
        }
        af[kk] = *(bf16x8*)tmp;
    }
    f32x4 acc[8];
#pragma unroll
    for (int ni = 0; ni < 8; ni++) acc[ni] = f32x4{0.f, 0.f, 0.f, 0.f};
#pragma unroll
    for (int ni = 0; ni < 8; ni++) {
        int oc = ni * 16 + l15;
        bf16x8 b0 = *(const bf16x8*)(sB + oc * 64 + sl * 8);
        bf16x8 b1 = *(const bf16x8*)(sB + oc * 64 + 32 + sl * 8);
        acc[ni] = __builtin_amdgcn_mfma_f32_16x16x32_bf16(af[0], b0, acc[ni], 0, 0, 0);
        acc[ni] = __builtin_amdgcn_mfma_f32_16x16x32_bf16(af[1], b1, acc[ni], 0, 0, 0);
    }
#pragma unroll
    for (int ni = 0; ni < 8; ni++) {
        int col = ni * 16 + l15;
        float bv = bias[col];
#pragma unroll
        for (int r = 0; r < 4; r++)
            sMB[(w * 16 + hi * 4 + r) * 128 + col] = actf<2>(acc[ni][r] + bv);
    }
    __syncthreads();
#pragma unroll
    for (int it = 0; it < 4; it++) {
        int idx = it * 256 + tid;
        int p = idx >> 4, c0 = (idx & 15) * 8;
        size_t base = (((size_t)b * 68 + y + 2) * 68 + p + 2) * 128 + c0;
        const float4* m4 = (const float4*)(sMB + p * 128 + c0);
        float4 lo = m4[0], hv = m4[1];
        int pk[4];
        pk[0] = pack2(lo.x, lo.y); pk[1] = pack2(lo.z, lo.w);
        pk[2] = pack2(hv.x, hv.y); pk[3] = pack2(hv.z, hv.w);
        *(int4*)(P0 + base) = *(int4*)pk;
    }
}

// ------------------------------- VQ argmin (MFMA) --------------------------
__global__ __launch_bounds__(256) void vq_argmin_k(const float* __restrict__ zr,
        const float* __restrict__ cb, int* __restrict__ ind) {
    __shared__ short sZ[2][128 * 32];
    __shared__ short sC[2][128 * 32];
    __shared__ float sN[128];
    const int tid = threadIdx.x;
    const int lane = tid & 63, wv = tid >> 6;
    const int pos0 = blockIdx.x * 128;
#pragma unroll
    for (int it = 0; it < 4; ++it) {
        int task = tid + it * 256;
        int row = task >> 3, kq = task & 7;
        const float4* zp = (const float4*)(zr + (size_t)(pos0 + row) * 64 + kq * 8);
        float4 v0 = zp[0], v1 = zp[1];
        int slot = ((kq & 3) ^ fof(row)) * 8;
        short tmp[8] = {f2bf(v0.x), f2bf(v0.y), f2bf(v0.z), f2bf(v0.w),
                        f2bf(v1.x), f2bf(v1.y), f2bf(v1.z), f2bf(v1.w)};
        *(bf16x8*)&sZ[kq >> 2][row * 32 + slot] = *(bf16x8*)tmp;
    }
    const int sslot = ((lane >> 4) ^ fof(lane & 15)) * 8;
    const int l15 = lane & 15;
    float best[2][4]; int bidx[2][4];
#pragma unroll
    for (int mi = 0; mi < 2; mi++)
#pragma unroll
        for (int r = 0; r < 4; r++) { best[mi][r] = INFINITY; bidx[mi][r] = 0; }
    for (int ch = 0; ch < 4; ++ch) {
        __syncthreads();
#pragma unroll
        for (int it = 0; it < 4; ++it) {
            int task = tid + it * 256;
            int row = task >> 3, kq = task & 7;
            const float4* cp = (const float4*)(cb + (size_t)(ch * 128 + row) * 64 + kq * 8);
            float4 v0 = cp[0], v1 = cp[1];
            int slot = ((kq & 3) ^ fof(row)) * 8;
            short tmp[8] = {f2bf(v0.x), f2bf(v0.y), f2bf(v0.z), f2bf(v0.w),
                            f2bf(v1.x), f2bf(v1.y), f2bf(v1.z), f2bf(v1.w)};
            *(bf16x8*)&sC[kq >> 2][row * 32 + slot] = *(bf16x8*)tmp;
        }
        if (tid < 128) {
            const float4* cp = (const float4*)(cb + (size_t)(ch * 128 + tid) * 64);
            float s = 0.f;
#pragma unroll
            for (int q = 0; q < 16; q++) {
                float4 v = cp[q];
                s += v.x * v.x + v.y * v.y + v.z * v.z + v.w * v.w;
            }
            sN[tid] = s;
        }
        __syncthreads();
        f32x4 acc[2][8];
#pragma unroll
        for (int mi = 0; mi < 2; mi++)
#pragma unroll
            for (int ni = 0; ni < 8; ni++) acc[mi][ni] = f32x4{0.f, 0.f, 0.f, 0.f};
#pragma unroll
        for (int kc = 0; kc < 2; ++kc) {
            bf16x8 za[2], ca[8];
#pragma unroll
            for (int mi = 0; mi < 2; mi++)
                za[mi] = *(const bf16x8*)&sZ[kc][(wv * 32 + mi * 16 + l15) * 32 + sslot];
#pragma unroll
            for (int ni = 0; ni < 8; ni++)
                ca[ni] = *(const bf16x8*)&sC[kc][(ni * 16 + l15) * 32 + sslot];
#pragma unroll
            for (int mi = 0; mi < 2; mi++)
#pragma unroll
                for (int ni = 0; ni < 8; ni++)
                    acc[mi][ni] = __builtin_amdgcn_mfma_f32_16x16x32_bf16(
                        za[mi], ca[ni], acc[mi][ni], 0, 0, 0);
        }
#pragma unroll
        for (int mi = 0; mi < 2; mi++)
#pragma unroll
            for (int ni = 0; ni < 8; ni++) {
                float nrm = sN[ni * 16 + l15];
                int idx = ch * 128 + ni * 16 + l15;
#pragma unroll
                for (int r = 0; r < 4; r++) {
                    float sc = nrm - 2.f * acc[mi][ni][r];
                    if (sc < best[mi][r]) { best[mi][r] = sc; bidx[mi][r] = idx; }
                }
            }
    }
#pragma unroll
    for (int m = 1; m < 16; m <<= 1) {
#pragma unroll
        for (int mi = 0; mi < 2; mi++)
#pragma unroll
            for (int r = 0; r < 4; r++) {
                float os = __shfl_xor(best[mi][r], m);
                int   oi = __shfl_xor(bidx[mi][r], m);
                if (os < best[mi][r] || (os == best[mi][r] && oi < bidx[mi][r])) {
                    best[mi][r] = os; bidx[mi][r] = oi;
                }
            }
    }
    if (l15 == 0) {
        int g = lane >> 4;
#pragma unroll
        for (int mi = 0; mi < 2; mi++)
#pragma unroll
            for (int r = 0; r < 4; r++)
                ind[pos0 + wv * 32 + mi * 16 + g * 4 + r] = bidx[mi][r];
    }
}

// -------------- VQ gather -> Pq padded bf16 + loss partials ----------------
__global__ __launch_bounds__(256) void vq_gather_k(const float* __restrict__ zr,
        const float* __restrict__ cb, const int* __restrict__ ind,
        short* __restrict__ q, float* __restrict__ part) {
    int pos = blockIdx.x * 256 + threadIdx.x;
    int b = pos >> 10, hw = pos & 1023, y = hw >> 5, xx = hw & 31;
    int idx = ind[pos];
    const float4* cp = (const float4*)(cb + (size_t)idx * 64);
    const float4* zp = (const float4*)(zr + (size_t)pos * 64);
    size_t qb = (((size_t)b * 36 + y + 2) * 36 + xx + 2) * 64;
    float sum = 0.f;
#pragma unroll
    for (int d4 = 0; d4 < 16; d4++) {
        float4 c = cp[d4], z = zp[d4];
        float dx = c.x - z.x, dy = c.y - z.y, dz = c.z - z.z, dw = c.w - z.w;
        sum += dx * dx + dy * dy + dz * dz + dw * dw;
        ((int*)(q + qb))[2 * d4] = pack2(c.x, c.y);
        ((int*)(q + qb))[2 * d4 + 1] = pack2(c.z, c.w);
    }
#pragma unroll
    for (int m = 1; m < 64; m <<= 1) sum += __shfl_xor(sum, m);
    __shared__ float sred[4];
    int lane = threadIdx.x & 63, wvv = threadIdx.x >> 6;
    if (lane == 0) sred[wvv] = sum;
    __syncthreads();
    if (threadIdx.x == 0)
        part[blockIdx.x] = sred[0] + sred[1] + sred[2] + sred[3];
}

__global__ void finalize_k(const float* __restrict__ part, float* __restrict__ out) {
    if (threadIdx.x == 0) {
        float s = 0.f;
        for (int k = 0; k < 64; k++) s += part[k];
        float m = s / 1048576.f;
        out[786432] = m;
        out[786433] = m;
    }
}

// -------- tw1: ConvT 4x4 s2 p1, 128->3, input padded-68 bf16, tanh ---------
__global__ __launch_bounds__(256) void tw1_k(const short* __restrict__ in,
        const float* __restrict__ W, const float* __restrict__ bias,
        float* __restrict__ out) {
    __shared__ float sW[16 * 128 * 4];
    int b = blockIdx.y, y0 = blockIdx.x * 8;
    int tid = threadIdx.x;
    for (int t = tid; t < 2048; t += 256) {
        int k = t >> 7, ic = t & 127;
        float4 v;
        v.x = W[((size_t)ic * 3 + 0) * 16 + k];
        v.y = W[((size_t)ic * 3 + 1) * 16 + k];
        v.z = W[((size_t)ic * 3 + 2) * 16 + k];
        v.w = 0.f;
        *(float4*)&sW[t * 4] = v;
    }
    __syncthreads();
    int r = tid >> 5, g = tid & 31;
    int oy = y0 + r, py = oy & 1, Y = oy >> 1, pxp = g & 1;
    float acc[4][3];
#pragma unroll
    for (int p = 0; p < 4; p++)
#pragma unroll
        for (int o = 0; o < 3; o++) acc[p][o] = 0.f;
#pragma unroll
    for (int my = 0; my < 2; my++) {
        int iy = Y + ((py == 0) ? -my : 1 - my) + 2;
        const short* rowp = in + (((size_t)b * 68 + iy) * 68) * 128;
        int ky = 2 * my + (py ^ 1);
#pragma unroll
        for (int mx = 0; mx < 2; mx++) {
            int kx = 2 * mx + (pxp ^ 1);
            int cof = ((pxp == 0) ? -mx : 1 - mx) + 2;
            const float* wbase = &sW[((ky * 4 + kx) * 128) * 4];
            const short* pptr[4];
#pragma unroll
            for (int p = 0; p < 4; p++) {
                int X = ((g + 32 * p) >> 1) + cof;
                pptr[p] = rowp + (size_t)X * 128;
            }
            for (int icb = 0; icb < 16; icb++) {
                bf16x8 v[4];
#pragma unroll
                for (int p = 0; p < 4; p++)
                    v[p] = *(const bf16x8*)(pptr[p] + icb * 8);
#pragma unroll
                for (int j = 0; j < 8; j++) {
                    float4 w = *(const float4*)&wbase[(icb * 8 + j) * 4];
#pragma unroll
                    for (int p = 0; p < 4; p++) {
                        float xv = bf2f(v[p][j]);
                        acc[p][0] += w.x * xv;
                        acc[p][1] += w.y * xv;
                        acc[p][2] += w.z * xv;
                    }
                }
            }
        }
    }
#pragma unroll
    for (int p = 0; p < 4; p++) {
        int ox = g + 32 * p;
#pragma unroll
        for (int o = 0; o < 3; o++)
            out[(((size_t)b * 3 + o) << 14) + oy * 128 + ox] =
                tanhf(acc[p][o] + bias[o]);
    }
}

// ---------------------------------------------------------------------------
extern "C" void kernel_launch(void* const* d_in, const int* in_sizes, int n_in,
                              void* d_out, int out_size, void* d_ws, size_t ws_size,
                              hipStream_t stream) {
    const float* x    = (const float*)d_in[0];
    const float* ew0  = (const float*)d_in[1];
    const float* eb0  = (const float*)d_in[2];
    const float* ew1  = (const float*)d_in[3];
    const float* eb1  = (const float*)d_in[4];
    const float* ew2  = (const float*)d_in[5];
    const float* eb2  = (const float*)d_in[6];
    const float* erw3 = (const float*)d_in[7];
    const float* erw1 = (const float*)d_in[8];
    const float* ew3  = (const float*)d_in[9];
    const float* eb3  = (const float*)d_in[10];
    const float* cbk  = (const float*)d_in[11];
    const float* dw0  = (const float*)d_in[12];
    const float* db0  = (const float*)d_in[13];
    const float* drw3 = (const float*)d_in[14];
    const float* drw1 = (const float*)d_in[15];
    const float* tw0  = (const float*)d_in[16];
    const float* tb0  = (const float*)d_in[17];
    const float* tw1  = (const float*)d_in[18];
    const float* tb1  = (const float*)d_in[19];
    float* out = (float*)d_out;

    short* S = (short*)d_ws;
    short* P0  = S;                       // [16][68][68][128]
    short* PB  = P0 + 9469952;            // [16][36][36][256]
    short* PC  = PB + 5308416;
    short* Pq  = PC + 5308416;            // [16][36][36][64]
    short* Wp1 = Pq + 1327104;
    short* We2 = Wp1 + 524288;
    short* Wer3 = We2 + 589824;
    short* We11 = Wer3 + 3538944;
    short* Wz   = We11 + 393216;
    short* Wd0  = Wz + 16384;
    short* Wdr3 = Wd0 + 147456;
    short* Wdr1 = Wdr3 + 3538944;
    short* Wt0  = Wdr1 + 393216;
    float* F   = (float*)(S + 31080448);
    float* Zr  = F;                       // [16384][64]
    float* PART = Zr + 1048576;
    int*   IND = (int*)(PART + 64);

    halo_all_k<<<1752, 256, 0, stream>>>(P0, PB, PC, Pq);
    prep_all_k<<<3792, 256, 0, stream>>>(ew1, ew2, erw3, erw1, ew3, dw0,
        drw3, drw1, tw0, Wp1, We2, Wer3, We11, Wz, Wd0, Wdr3, Wdr1, Wt0);

    // ---------------- encoder ----------------
    conv0_k<<<dim3(64, 16), 256, 0, stream>>>(x, ew0, eb0, P0);
    rconv_k<128, 16, 2, 2, 68, 2, true, false>
        <<<256, 512, 0, stream>>>(P0, Wp1, eb1, nullptr, PB);
    rconv_k<256, 9, 1, 1, 36, 2, true, false>
        <<<256, 512, 0, stream>>>(PB, We2, eb2, nullptr, PC);
    for (int i = 0; i < 6; i++) {
        short* inb  = (i & 1) ? PB : PC;
        short* outb = (i & 1) ? PC : PB;
        if (i < 5)
            rconv_k<256, 9, 1, 1, 36, 0, false, true>
                <<<256, 512, 0, stream>>>(inb, Wer3 + (size_t)i * 589824,
                    nullptr, We11 + (size_t)i * 65536, outb);
        else
            rconv_k<256, 9, 1, 1, 36, 2, false, true>
                <<<256, 512, 0, stream>>>(inb, Wer3 + (size_t)i * 589824,
                    nullptr, We11 + (size_t)i * 65536, outb);
    }
    gconv_k<256, 64, 1, 0, 1, 36, 2, false, true, 1, 64>
        <<<dim3(128, 1), 256, 0, stream>>>(PC, Wz, eb3, nullptr, Zr);

    // ---------------- vector quantization ----------------
    vq_argmin_k<<<128, 256, 0, stream>>>(Zr, cbk, IND);
    vq_gather_k<<<64, 256, 0, stream>>>(Zr, cbk, IND, Pq, PART);

    // ---------------- decoder ----------------
    rconv_k<64, 9, 1, 1, 36, 2, true, false>
        <<<256, 512, 0, stream>>>(Pq, Wd0, db0, nullptr, PC);
    for (int i = 0; i < 6; i++) {
        short* inb  = (i & 1) ? PB : PC;
        short* outb = (i & 1) ? PC : PB;
        if (i < 5)
            rconv_k<256, 9, 1, 1, 36, 0, false, true>
                <<<256, 512, 0, stream>>>(inb, Wdr3 + (size_t)i * 589824,
                    nullptr, Wdr1 + (size_t)i * 65536, outb);
        else
            rconv_k<256, 9, 1, 1, 36, 2, false, true>
                <<<256, 512, 0, stream>>>(inb, Wdr3 + (size_t)i * 589824,
                    nullptr, Wdr1 + (size_t)i * 65536, outb);
    }
    gconv_k<256, 128, 4, 3, 1, 36, 2, false, true, 2, 128>
        <<<dim3(128, 1, 4), 256, 0, stream>>>(PC, Wt0, tb0, nullptr, P0);
    tw1_k<<<dim3(16, 16), 256, 0, stream>>>(P0, tw1, tb1, out);

    finalize_k<<<1, 64, 0, stream>>>(PART, out);
}

// Round 13
// 582.950 us; speedup vs baseline: 1.0230x; 1.0230x over previous
//
#include <hip/hip_runtime.h>
#include <math.h>

// ---------------------------------------------------------------------------
// VQ-VAE forward. bf16 MFMA implicit-GEMM.  (Round-11 structure + XCD-aware
// block swizzle in rconv: each XCD owns 2 contiguous images -> L2-local halos.)
// rconv_k: 16 waves (1024 thr) = 2M x 4N x 2Kg; wave tile 32x64xK/2;
// 3-buf counted-vmcnt staging; kg-merge via LDS; coalesced epilogue;
// fused residual-1x1 phase2. conv0_k: MFMA implicit GEMM (K=48 pad 64).
// ---------------------------------------------------------------------------

typedef __attribute__((ext_vector_type(8))) short bf16x8;
typedef __attribute__((ext_vector_type(4))) float f32x4;

__device__ __forceinline__ float bf2f(short s) {
    unsigned u = ((unsigned)(unsigned short)s) << 16;
    return __builtin_bit_cast(float, u);
}
__device__ __forceinline__ unsigned short f2bfu(float f) {
    unsigned u = __builtin_bit_cast(unsigned, f);
    u = (u + 0x7fff + ((u >> 16) & 1)) >> 16;
    return (unsigned short)u;
}
__device__ __forceinline__ short f2bf(float f) { return (short)f2bfu(f); }
__device__ __forceinline__ int pack2(float a, float b) {
    return (int)f2bfu(a) | ((int)f2bfu(b) << 16);
}

template<int ACT>
__device__ __forceinline__ float actf(float v) {
    if (ACT == 1) return fmaxf(v, 0.f);
    if (ACT == 2) return v > 0.f ? v : 0.01f * v;
    return v;
}

__device__ __forceinline__ void gload_lds16(const void* g, void* l) {
    __builtin_amdgcn_global_load_lds(
        (const __attribute__((address_space(1))) unsigned int*)g,
        (__attribute__((address_space(3))) unsigned int*)l, 16, 0, 0);
}

__device__ __forceinline__ int fof(int r) { return (r & 3) ^ ((r >> 2) & 3); }

#define WAITV(N) asm volatile("s_waitcnt vmcnt(" #N ")" ::: "memory")
#define LGKM0 asm volatile("s_waitcnt lgkmcnt(0)" ::: "memory")

// ---------- weight prep: LDS-tiled transpose (coalesced both sides) --------
__device__ __forceinline__ void prep_t(const float* __restrict__ src,
        short* __restrict__ dst, int COUT, int CIN, int T, int TP,
        int blk, float* sT, int tid) {
    int opc = COUT >> 2;
    int c = blk / opc, oc0 = (blk - c * opc) * 4;
    const float* s = src + ((size_t)c * COUT + oc0) * CIN * T;
    int n = 4 * CIN * T;
    for (int i = tid; i < n; i += 256) {
        int ocl = i / (CIN * T); int rem = i - ocl * (CIN * T);
        int ic = rem / T, t = rem - ic * T;
        sT[(ocl * CIN + ic) * TP + t] = s[i];
    }
    __syncthreads();
    for (int i = tid; i < n; i += 256) {
        int t = i / (4 * CIN); int rem = i - t * (4 * CIN);
        int ocl = rem / CIN, ic = rem - ocl * CIN;
        dst[(((size_t)c * T + t) * COUT + oc0 + ocl) * CIN + ic]
            = f2bf(sT[(ocl * CIN + ic) * TP + t]);
    }
    __syncthreads();
}

__global__ __launch_bounds__(256) void prep_all_k(
        const float* ew1, const float* ew2, const float* erw3,
        const float* erw1, const float* ew3, const float* dw0,
        const float* drw3, const float* drw1, const float* tw0,
        short* Wp1, short* We2, short* Wer3, short* We11, short* Wz,
        short* Wd0, short* Wdr3, short* Wdr1, short* Wt0) {
    __shared__ float sT[9216];
    int bid = blockIdx.x, tid = threadIdx.x;
    if (bid < 64)        prep_t(ew1, Wp1, 256, 128, 16, 17, bid, sT, tid);
    else if (bid < 128)  prep_t(ew2, We2, 256, 256, 9, 9, bid - 64, sT, tid);
    else if (bid < 512)  prep_t(erw3, Wer3, 256, 256, 9, 9, bid - 128, sT, tid);
    else if (bid < 896)  prep_t(erw1, We11, 256, 256, 1, 1, bid - 512, sT, tid);
    else if (bid < 912)  prep_t(ew3, Wz, 64, 256, 1, 1, bid - 896, sT, tid);
    else if (bid < 976)  prep_t(dw0, Wd0, 256, 64, 9, 9, bid - 912, sT, tid);
    else if (bid < 1360) prep_t(drw3, Wdr3, 256, 256, 9, 9, bid - 976, sT, tid);
    else if (bid < 1744) prep_t(drw1, Wdr1, 256, 256, 1, 1, bid - 1360, sT, tid);
    else {
        int i = (bid - 1744) * 256 + tid;
        if (i < 524288) {
            int ic = i & 255; int r = i >> 8;
            int oc = r & 127; r >>= 7;
            int tap = r & 3; int par = r >> 2;
            int py = par >> 1, px = par & 1, my = tap >> 1, mx = tap & 1;
            int ky = 2 * my + (py ^ 1), kx = 2 * mx + (px ^ 1);
            Wt0[i] = f2bf(tw0[(((size_t)ic * 128 + oc) * 4 + ky) * 4 + kx]);
        }
    }
}

// ------------------ halo zero (all 4 buffers, one dispatch) ----------------
__global__ __launch_bounds__(256) void halo_all_k(short* P0, short* PB,
        short* PC, short* Pq) {
    int g = blockIdx.x * 256 + threadIdx.x;
    short* base; int W, C, idx;
    if (g < 135168)      { base = P0; W = 68; C = 128; idx = g; }
    else if (g < 274432) { base = PB; W = 36; C = 256; idx = g - 135168; }
    else if (g < 413696) { base = PC; W = 36; C = 256; idx = g - 274432; }
    else                 { base = Pq; W = 36; C = 64;  idx = g - 413696; }
    int c8 = C >> 3;
    int per_img = (4 * W + (W - 4) * 4) * c8;
    int img = idx / per_img, r = idx - img * per_img;
    int row, off;
    if (r < 4 * W * c8) {
        int rr = r / (W * c8);
        row = (rr < 2) ? rr : W - 4 + rr;
        off = r - rr * (W * c8);
    } else {
        int r2 = r - 4 * W * c8;
        row = 2 + r2 / (4 * c8);
        int q = r2 - (row - 2) * (4 * c8);
        off = (q < 2 * c8) ? q : (W - 2) * c8 + (q - 2 * c8);
    }
    ((int4*)(base + ((size_t)img * W + row) * W * C))[off] = int4{0, 0, 0, 0};
}

// ------------- rconv: 16-wave (1024 thr) BM=64 BN=256 conv -----------------
// XCD swizzle: logical tile = (bid%8)*32 + bid/8 (bijective, 256 blocks).
template<int CIN, int NTAPS, int TAPPAT, int SM, int INW, int OUTACT,
         bool HASB, bool FUSE>
__global__ __launch_bounds__(1024, 1) void rconv_k(
        const short* __restrict__ in, const short* __restrict__ Wp,
        const float* __restrict__ bias, const short* __restrict__ W1p,
        short* __restrict__ outp) {
    constexpr int CH64 = (CIN >= 128) ? CIN / 64 : 1;
    constexpr int LG2 = (CH64 == 4) ? 2 : (CH64 == 2) ? 1 : 0;
    constexpr int ST = NTAPS * CH64;
    __shared__ short sLds[81920];
    const int tid = threadIdx.x;
    const int lane = tid & 63, wv = tid >> 6;
    const int wc = wv & 3, mh = (wv >> 2) & 1, kg = wv >> 3;
    const int tile = (blockIdx.x & 7) * 32 + (blockIdx.x >> 3);
    const int pix0 = tile * 64;
    const int l15 = lane & 15, hi = lane >> 4;
    const int sl = hi ^ fof(l15);
    const bool low = (tid < 512);

    const short* Aptr = in;
    if (low) {
        int arow = tid >> 3, aslot = tid & 7;
        int pixa = pix0 + arow;
        int ba = pixa >> 10, Ya = (pixa >> 5) & 31, Xa = pixa & 31;
        Aptr = in + (size_t)((ba * INW + SM * Ya + 2) * INW + (SM * Xa + 2)) * CIN
             + (aslot >> 2) * 32 + (((aslot & 3) ^ fof(arow)) * 8);
    }
    const short* Bptr[2];
#pragma unroll
    for (int j = 0; j < 2; j++) {
        int gb = tid + 1024 * j;
        int kkb = gb >> 10, oc = (gb >> 2) & 255, slb = gb & 3;
        Bptr[j] = Wp + (size_t)oc * CIN + kkb * 32 + ((slb ^ fof(oc)) * 8);
    }

    auto stage = [&](int s, int bi) {
        int t = s >> LG2;
        int c0 = (s & (CH64 - 1)) * 64;
        int rof, cof;
        if (TAPPAT == 1) { rof = t / 3 - 1; cof = t % 3 - 1; }
        else             { rof = (t >> 2) - 1; cof = (t & 3) - 1; }
        char* L = (char*)sLds + bi * 40960;
        if (low)
            gload_lds16(Aptr + (rof * INW + cof) * CIN + c0, L + tid * 16);
        int woff = t * (256 * CIN) + c0;
        gload_lds16(Bptr[0] + woff, L + 8192 + tid * 16);
        gload_lds16(Bptr[1] + woff, L + 8192 + (tid + 1024) * 16);
    };

    f32x4 acc[2][4];
#pragma unroll
    for (int mi = 0; mi < 2; mi++)
#pragma unroll
        for (int ni = 0; ni < 4; ni++) acc[mi][ni] = f32x4{0.f, 0.f, 0.f, 0.f};

    stage(0, 0);
    stage(1, 1);
    int bi = 0;
    for (int s = 0; s < ST; ++s) {
        if (s < ST - 1) { if (low) { WAITV(3); } else { WAITV(2); } }
        else { WAITV(0); }
        __builtin_amdgcn_s_barrier();
        int nx = bi + 2; if (nx >= 3) nx -= 3;
        if (s + 2 < ST) stage(s + 2, nx);
        const short* LA = sLds + bi * 20480;
        const short* LB = LA + 4096;
        bf16x8 af[2], bfr[4];
#pragma unroll
        for (int mi = 0; mi < 2; mi++)
            af[mi] = *(const bf16x8*)(LA + (mh * 32 + mi * 16 + l15) * 64
                                      + kg * 32 + sl * 8);
#pragma unroll
        for (int ni = 0; ni < 4; ni++)
            bfr[ni] = *(const bf16x8*)(LB + kg * 8192
                                       + (wc * 64 + ni * 16 + l15) * 32 + sl * 8);
        __builtin_amdgcn_s_setprio(1);
#pragma unroll
        for (int mi = 0; mi < 2; mi++)
#pragma unroll
            for (int ni = 0; ni < 4; ni++)
                acc[mi][ni] = __builtin_amdgcn_mfma_f32_16x16x32_bf16(
                    af[mi], bfr[ni], acc[mi][ni], 0, 0, 0);
        __builtin_amdgcn_s_setprio(0);
        bi = (bi == 2) ? 0 : bi + 1;
    }

    float* MB = (float*)sLds;

    __syncthreads();
    if (kg == 1) {
#pragma unroll
        for (int mi = 0; mi < 2; mi++)
#pragma unroll
            for (int ni = 0; ni < 4; ni++)
#pragma unroll
                for (int r = 0; r < 4; r++)
                    MB[(mh * 32 + mi * 16 + hi * 4 + r) * 256
                       + wc * 64 + ni * 16 + l15] = acc[mi][ni][r];
    }
    __syncthreads();

    if (!FUSE) {
        if (kg == 0) {
#pragma unroll
            for (int mi = 0; mi < 2; mi++)
#pragma unroll
                for (int ni = 0; ni < 4; ni++) {
                    int col = wc * 64 + ni * 16 + l15;
                    float b = HASB ? bias[col] : 0.f;
#pragma unroll
                    for (int r = 0; r < 4; r++) {
                        int row = mh * 32 + mi * 16 + hi * 4 + r;
                        MB[row * 256 + col] += acc[mi][ni][r] + b;
                    }
                }
        }
        __syncthreads();
#pragma unroll
        for (int j = 0; j < 2; j++) {
            int idx = j * 1024 + tid;
            int p = idx >> 5, c0 = (idx & 31) * 8;
            int pix = pix0 + p;
            int b = pix >> 10, Y = (pix >> 5) & 31, X = pix & 31;
            size_t base = (((size_t)b * 36 + Y + 2) * 36 + X + 2) * 256 + c0;
            const float4* m4 = (const float4*)(MB + p * 256 + c0);
            float4 lo = m4[0], hv = m4[1];
            int pk[4];
            pk[0] = pack2(actf<OUTACT>(lo.x), actf<OUTACT>(lo.y));
            pk[1] = pack2(actf<OUTACT>(lo.z), actf<OUTACT>(lo.w));
            pk[2] = pack2(actf<OUTACT>(hv.x), actf<OUTACT>(hv.y));
            pk[3] = pack2(actf<OUTACT>(hv.z), actf<OUTACT>(hv.w));
            *(int4*)(outp + base) = *(int4*)pk;
        }
        return;
    }

    // ---------------- FUSE: W1 prefetch + h -> H (relu, bf16) ---------------
    const short* W1ptr[2];
#pragma unroll
    for (int j = 0; j < 2; j++) {
        int gb = tid + 1024 * j;
        int kkb = gb >> 10, oc = (gb >> 2) & 255, slb = gb & 3;
        W1ptr[j] = W1p + (size_t)oc * 256 + kkb * 32 + ((slb ^ fof(oc)) * 8);
    }
    auto stage2 = [&](int c) {
        char* L = (char*)sLds + 98304 + (c & 1) * 32768;
        gload_lds16(W1ptr[0] + c * 64, L + tid * 16);
        gload_lds16(W1ptr[1] + c * 64, L + (tid + 1024) * 16);
    };
    stage2(0);
    stage2(1);

    short* H = sLds + 32768;
    if (kg == 0) {
#pragma unroll
        for (int mi = 0; mi < 2; mi++)
#pragma unroll
            for (int ni = 0; ni < 4; ni++) {
                int col = wc * 64 + ni * 16 + l15;
#pragma unroll
                for (int r = 0; r < 4; r++) {
                    int row = mh * 32 + mi * 16 + hi * 4 + r;
                    float v = acc[mi][ni][r] + MB[row * 256 + col];
                    H[((col >> 5) * 64 + row) * 32
                      + (((col >> 3) & 3) ^ fof(row)) * 8 + (col & 7)]
                        = f2bf(fmaxf(v, 0.f));
                }
            }
    }
    LGKM0;
    __builtin_amdgcn_sched_barrier(0);
    __builtin_amdgcn_s_barrier();

    f32x4 acc2[2][4];
#pragma unroll
    for (int mi = 0; mi < 2; mi++)
#pragma unroll
        for (int ni = 0; ni < 4; ni++) acc2[mi][ni] = f32x4{0.f, 0.f, 0.f, 0.f};

    for (int s2 = 0; s2 < 4; ++s2) {
        if (s2 < 3) { WAITV(2); } else { WAITV(0); }
        __builtin_amdgcn_s_barrier();
        int c = s2 * 2 + kg;
        const short* LW = sLds + 49152 + (s2 & 1) * 16384 + kg * 8192;
        bf16x8 af2[2], bf2r[4];
#pragma unroll
        for (int mi = 0; mi < 2; mi++) {
            int row = mh * 32 + mi * 16 + l15;
            af2[mi] = *(const bf16x8*)(H + (c * 64 + row) * 32
                                       + (hi ^ fof(row)) * 8);
        }
#pragma unroll
        for (int ni = 0; ni < 4; ni++)
            bf2r[ni] = *(const bf16x8*)(LW + (wc * 64 + ni * 16 + l15) * 32
                                        + sl * 8);
        LGKM0;
        __builtin_amdgcn_sched_barrier(0);
        __builtin_amdgcn_s_barrier();
        if (s2 < 2) stage2(s2 + 2);
        __builtin_amdgcn_s_setprio(1);
#pragma unroll
        for (int mi = 0; mi < 2; mi++)
#pragma unroll
            for (int ni = 0; ni < 4; ni++)
                acc2[mi][ni] = __builtin_amdgcn_mfma_f32_16x16x32_bf16(
                    af2[mi], bf2r[ni], acc2[mi][ni], 0, 0, 0);
        __builtin_amdgcn_s_setprio(0);
    }

    __syncthreads();
    if (kg == 1) {
#pragma unroll
        for (int mi = 0; mi < 2; mi++)
#pragma unroll
            for (int ni = 0; ni < 4; ni++)
#pragma unroll
                for (int r = 0; r < 4; r++)
                    MB[(mh * 32 + mi * 16 + hi * 4 + r) * 256
                       + wc * 64 + ni * 16 + l15] = acc2[mi][ni][r];
    }
    __syncthreads();
    if (kg == 0) {
#pragma unroll
        for (int mi = 0; mi < 2; mi++)
#pragma unroll
            for (int ni = 0; ni < 4; ni++) {
                int col = wc * 64 + ni * 16 + l15;
#pragma unroll
                for (int r = 0; r < 4; r++) {
                    int row = mh * 32 + mi * 16 + hi * 4 + r;
                    MB[row * 256 + col] += acc2[mi][ni][r];
                }
            }
    }
    __syncthreads();
#pragma unroll
    for (int j = 0; j < 2; j++) {
        int idx = j * 1024 + tid;
        int p = idx >> 5, c0 = (idx & 31) * 8;
        int pix = pix0 + p;
        int b = pix >> 10, Y = (pix >> 5) & 31, X = pix & 31;
        size_t base = (((size_t)b * 36 + Y + 2) * 36 + X + 2) * 256 + c0;
        const float4* m4 = (const float4*)(MB + p * 256 + c0);
        float4 lo = m4[0], hv = m4[1];
        bf16x8 rv = *(const bf16x8*)(in + base);
        int pk[4];
        pk[0] = pack2(actf<OUTACT>(lo.x + bf2f(rv[0])),
                      actf<OUTACT>(lo.y + bf2f(rv[1])));
        pk[1] = pack2(actf<OUTACT>(lo.z + bf2f(rv[2])),
                      actf<OUTACT>(lo.w + bf2f(rv[3])));
        pk[2] = pack2(actf<OUTACT>(hv.x + bf2f(rv[4])),
                      actf<OUTACT>(hv.y + bf2f(rv[5])));
        pk[3] = pack2(actf<OUTACT>(hv.z + bf2f(rv[6])),
                      actf<OUTACT>(hv.w + bf2f(rv[7])));
        *(int4*)(outp + base) = *(int4*)pk;
    }
}

// ------------------- 4-wave gconv (tw0 parities, ew3) ----------------------
template<int CIN, int COUT, int NTAPS, int TAPPAT, int SM, int INW,
         int OUTACT, bool RES, bool HASB, int OUTMODE, int BN>
__global__ __launch_bounds__(256) void gconv_k(
        const short* __restrict__ in, const short* __restrict__ Wp,
        const float* __restrict__ bias, const short* __restrict__ res,
        void* __restrict__ outp) {
    constexpr int KCH = CIN / 32;
    constexpr int LG = (KCH == 8) ? 3 : (KCH == 4) ? 2 : (KCH == 2) ? 1 : 0;
    constexpr int ST = NTAPS * KCH;
    constexpr int NF = BN / 32;
    constexpr int WN = BN / 2;
    __shared__ short sA[3 * 128 * 32];
    __shared__ short sB[3 * BN * 32];
    const int tid = threadIdx.x;
    const int lane = tid & 63, wv = tid >> 6;
    const int wr = wv >> 1, wc = wv & 1;
    const int pix0 = blockIdx.x * 128;
    const int oc0 = blockIdx.y * BN;
    int py = 0, px = 0;
    if (TAPPAT == 3) {
        int par = blockIdx.z;
        py = par >> 1; px = par & 1;
        Wp += (size_t)par * NTAPS * COUT * CIN;
    }
    const int sp = tid >> 2;
    const int swz = ((tid & 3) ^ fof(sp)) * 8;
    int rbA[2];
#pragma unroll
    for (int rd = 0; rd < 2; rd++) {
        int pix = pix0 + sp + rd * 64;
        int b = pix >> 10, Y = (pix >> 5) & 31, X = pix & 31;
        rbA[rd] = ((b * INW + SM * Y + 2) * INW + (SM * X + 2)) * CIN + swz;
    }
    const int wb0 = (oc0 + sp) * CIN + swz;
    const int wb1 = (oc0 + sp + 64) * CIN + swz;

    f32x4 acc[4][NF];
#pragma unroll
    for (int i = 0; i < 4; i++)
#pragma unroll
        for (int j = 0; j < NF; j++) acc[i][j] = f32x4{0.f, 0.f, 0.f, 0.f};

    const int sslot = ((lane >> 4) ^ fof(lane & 15)) * 8;
    const int abase = (wr * 64 + (lane & 15)) * 32 + sslot;
    const int bbase = (wc * WN + (lane & 15)) * 32 + sslot;

    auto stage = [&](int s, int biq) {
        int t = s >> LG, c = s & (KCH - 1);
        int rof, cof;
        if (TAPPAT == 0) { rof = 0; cof = 0; }
        else if (TAPPAT == 1) { rof = t / 3 - 1; cof = t % 3 - 1; }
        else if (TAPPAT == 2) { rof = t / 4 - 1; cof = t % 4 - 1; }
        else { int my = t >> 1, mx = t & 1;
               rof = (py == 0) ? -my : 1 - my;
               cof = (px == 0) ? -mx : 1 - mx; }
        const int tapoff = (rof * INW + cof) * CIN + c * 32;
        char* a = (char*)sA + biq * 8192;
        char* b = (char*)sB + biq * (BN * 64);
        const short* wt = Wp + (size_t)t * COUT * CIN + c * 32;
        gload_lds16(in + rbA[0] + tapoff, a + tid * 16);
        gload_lds16(in + rbA[1] + tapoff, a + 4096 + tid * 16);
        gload_lds16(wt + wb0, b + tid * 16);
        if (BN == 128) gload_lds16(wt + wb1, b + 4096 + tid * 16);
    };

    stage(0, 0);
    stage(1, 1);
    int cur = 0;
    for (int s = 0; s < ST; ++s) {
        if (s < ST - 1) {
            if (BN == 128) { WAITV(4); } else { WAITV(3); }
        } else {
            WAITV(0);
        }
        __builtin_amdgcn_s_barrier();
        int nxt = cur + 2; if (nxt >= 3) nxt -= 3;
        if (s + 2 < ST) stage(s + 2, nxt);
        const short* a = sA + cur * 4096;
        const short* b = sB + cur * (BN * 32);
        bf16x8 af[4], bfm[NF];
#pragma unroll
        for (int mi = 0; mi < 4; mi++)
            af[mi] = *(const bf16x8*)(a + abase + mi * 512);
#pragma unroll
        for (int ni = 0; ni < NF; ni++)
            bfm[ni] = *(const bf16x8*)(b + bbase + ni * 512);
        __builtin_amdgcn_s_setprio(1);
#pragma unroll
        for (int mi = 0; mi < 4; mi++)
#pragma unroll
            for (int ni = 0; ni < NF; ni++)
                acc[mi][ni] = __builtin_amdgcn_mfma_f32_16x16x32_bf16(
                    af[mi], bfm[ni], acc[mi][ni], 0, 0, 0);
        __builtin_amdgcn_s_setprio(0);
        cur = (cur == 2) ? 0 : cur + 1;
    }
#pragma unroll
    for (int mi = 0; mi < 4; mi++) {
#pragma unroll
        for (int r = 0; r < 4; r++) {
            int pix = pix0 + wr * 64 + mi * 16 + (lane >> 4) * 4 + r;
            int b = pix >> 10, Y = (pix >> 5) & 31, X = pix & 31;
            size_t rowoff = 0;
            if (OUTMODE == 0)
                rowoff = (((size_t)b * 36 + Y + 2) * 36 + X + 2) * COUT;
            else if (OUTMODE == 2)
                rowoff = (((size_t)b * 68 + 2 * Y + py + 2) * 68 + 2 * X + px + 2) * 128;
#pragma unroll
            for (int ni = 0; ni < NF; ni++) {
                int col = oc0 + wc * WN + ni * 16 + (lane & 15);
                float v = acc[mi][ni][r];
                if (HASB) v += bias[col];
                if (OUTMODE == 1) {
                    ((float*)outp)[(size_t)pix * COUT + col] = actf<OUTACT>(v);
                } else {
                    size_t off = rowoff + col;
                    if (RES) v += bf2f(res[off]);
                    ((short*)outp)[off] = f2bf(actf<OUTACT>(v));
                }
            }
        }
    }
}

// --------------- conv0: 4x4 s2 p1, Cin=3, MFMA implicit GEMM ---------------
__global__ __launch_bounds__(256) void conv0_k(const float* __restrict__ x,
        const float* __restrict__ W, const float* __restrict__ bias,
        short* __restrict__ P0) {
    __shared__ float sP[3 * 4 * 132];
    __shared__ short sB[8192];
    __shared__ float sMB[8192];
    int y = blockIdx.x, b = blockIdx.y;
    int tid = threadIdx.x;
    int lane = tid & 63, w = tid >> 6;
    int l15 = lane & 15, hi = lane >> 4;
    int sl = hi ^ fof(l15);
    for (int t = tid; t < 8192; t += 256) {
        int oc = t >> 6, k = t & 63;
        float v = (k < 48) ? W[(size_t)oc * 48 + k] : 0.f;
        int kk = k >> 5, slot = (k >> 3) & 3, j = k & 7;
        sB[oc * 64 + kk * 32 + ((slot ^ fof(oc)) * 8) + j] = f2bf(v);
    }
    for (int t = tid; t < 1560; t += 256) {
        int ic = t / 520; int r = t - ic * 520;
        int ry = r / 130, rx = r - ry * 130;
        int iy = 2 * y - 1 + ry, ix = rx - 1;
        float v = 0.f;
        if ((unsigned)iy < 128u && (unsigned)ix < 128u)
            v = x[((size_t)b * 3 + ic) * 16384 + iy * 128 + ix];
        sP[(ic * 4 + ry) * 132 + rx] = v;
    }
    __syncthreads();
    int ox = w * 16 + l15;
    bf16x8 af[2];
#pragma unroll
    for (int kk = 0; kk < 2; kk++) {
        short tmp[8];
#pragma unroll
        for (int j = 0; j < 8; j++) {
            int k = kk * 32 + hi * 8 + j;
            float v = 0.f;
            if (k < 48) {
                int ic = k >> 4, ky = (k >> 2) & 3, kx = k & 3;
                v = sP[(ic * 4 + ky) * 132 + 2 * ox + kx];
            }
            tmp[j] = f2bf(v);
        }
        af[kk] = *(bf16x8*)tmp;
    }
    f32x4 acc[8];
#pragma unroll
    for (int ni = 0; ni < 8; ni++) acc[ni] = f32x4{0.f, 0.f, 0.f, 0.f};
#pragma unroll
    for (int ni = 0; ni < 8; ni++) {
        int oc = ni * 16 + l15;
        bf16x8 b0 = *(const bf16x8*)(sB + oc * 64 + sl * 8);
        bf16x8 b1 = *(const bf16x8*)(sB + oc * 64 + 32 + sl * 8);
        acc[ni] = __builtin_amdgcn_mfma_f32_16x16x32_bf16(af[0], b0, acc[ni], 0, 0, 0);
        acc[ni] = __builtin_amdgcn_mfma_f32_16x16x32_bf16(af[1], b1, acc[ni], 0, 0, 0);
    }
#pragma unroll
    for (int ni = 0; ni < 8; ni++) {
        int col = ni * 16 + l15;
        float bv = bias[col];
#pragma unroll
        for (int r = 0; r < 4; r++)
            sMB[(w * 16 + hi * 4 + r) * 128 + col] = actf<2>(acc[ni][r] + bv);
    }
    __syncthreads();
#pragma unroll
    for (int it = 0; it < 4; it++) {
        int idx = it * 256 + tid;
        int p = idx >> 4, c0 = (idx & 15) * 8;
        size_t base = (((size_t)b * 68 + y + 2) * 68 + p + 2) * 128 + c0;
        const float4* m4 = (const float4*)(sMB + p * 128 + c0);
        float4 lo = m4[0], hv = m4[1];
        int pk[4];
        pk[0] = pack2(lo.x, lo.y); pk[1] = pack2(lo.z, lo.w);
        pk[2] = pack2(hv.x, hv.y); pk[3] = pack2(hv.z, hv.w);
        *(int4*)(P0 + base) = *(int4*)pk;
    }
}

// ------------------------------- VQ argmin (MFMA) --------------------------
__global__ __launch_bounds__(256) void vq_argmin_k(const float* __restrict__ zr,
        const float* __restrict__ cb, int* __restrict__ ind) {
    __shared__ short sZ[2][128 * 32];
    __shared__ short sC[2][128 * 32];
    __shared__ float sN[128];
    const int tid = threadIdx.x;
    const int lane = tid & 63, wv = tid >> 6;
    const int pos0 = blockIdx.x * 128;
#pragma unroll
    for (int it = 0; it < 4; ++it) {
        int task = tid + it * 256;
        int row = task >> 3, kq = task & 7;
        const float4* zp = (const float4*)(zr + (size_t)(pos0 + row) * 64 + kq * 8);
        float4 v0 = zp[0], v1 = zp[1];
        int slot = ((kq & 3) ^ fof(row)) * 8;
        short tmp[8] = {f2bf(v0.x), f2bf(v0.y), f2bf(v0.z), f2bf(v0.w),
                        f2bf(v1.x), f2bf(v1.y), f2bf(v1.z), f2bf(v1.w)};
        *(bf16x8*)&sZ[kq >> 2][row * 32 + slot] = *(bf16x8*)tmp;
    }
    const int sslot = ((lane >> 4) ^ fof(lane & 15)) * 8;
    const int l15 = lane & 15;
    float best[2][4]; int bidx[2][4];
#pragma unroll
    for (int mi = 0; mi < 2; mi++)
#pragma unroll
        for (int r = 0; r < 4; r++) { best[mi][r] = INFINITY; bidx[mi][r] = 0; }
    for (int ch = 0; ch < 4; ++ch) {
        __syncthreads();
#pragma unroll
        for (int it = 0; it < 4; ++it) {
            int task = tid + it * 256;
            int row = task >> 3, kq = task & 7;
            const float4* cp = (const float4*)(cb + (size_t)(ch * 128 + row) * 64 + kq * 8);
            float4 v0 = cp[0], v1 = cp[1];
            int slot = ((kq & 3) ^ fof(row)) * 8;
            short tmp[8] = {f2bf(v0.x), f2bf(v0.y), f2bf(v0.z), f2bf(v0.w),
                            f2bf(v1.x), f2bf(v1.y), f2bf(v1.z), f2bf(v1.w)};
            *(bf16x8*)&sC[kq >> 2][row * 32 + slot] = *(bf16x8*)tmp;
        }
        if (tid < 128) {
            const float4* cp = (const float4*)(cb + (size_t)(ch * 128 + tid) * 64);
            float s = 0.f;
#pragma unroll
            for (int q = 0; q < 16; q++) {
                float4 v = cp[q];
                s += v.x * v.x + v.y * v.y + v.z * v.z + v.w * v.w;
            }
            sN[tid] = s;
        }
        __syncthreads();
        f32x4 acc[2][8];
#pragma unroll
        for (int mi = 0; mi < 2; mi++)
#pragma unroll
            for (int ni = 0; ni < 8; ni++) acc[mi][ni] = f32x4{0.f, 0.f, 0.f, 0.f};
#pragma unroll
        for (int kc = 0; kc < 2; ++kc) {
            bf16x8 za[2], ca[8];
#pragma unroll
            for (int mi = 0; mi < 2; mi++)
                za[mi] = *(const bf16x8*)&sZ[kc][(wv * 32 + mi * 16 + l15) * 32 + sslot];
#pragma unroll
            for (int ni = 0; ni < 8; ni++)
                ca[ni] = *(const bf16x8*)&sC[kc][(ni * 16 + l15) * 32 + sslot];
#pragma unroll
            for (int mi = 0; mi < 2; mi++)
#pragma unroll
                for (int ni = 0; ni < 8; ni++)
                    acc[mi][ni] = __builtin_amdgcn_mfma_f32_16x16x32_bf16(
                        za[mi], ca[ni], acc[mi][ni], 0, 0, 0);
        }
#pragma unroll
        for (int mi = 0; mi < 2; mi++)
#pragma unroll
            for (int ni = 0; ni < 8; ni++) {
                float nrm = sN[ni * 16 + l15];
                int idx = ch * 128 + ni * 16 + l15;
#pragma unroll
                for (int r = 0; r < 4; r++) {
                    float sc = nrm - 2.f * acc[mi][ni][r];
                    if (sc < best[mi][r]) { best[mi][r] = sc; bidx[mi][r] = idx; }
                }
            }
    }
#pragma unroll
    for (int m = 1; m < 16; m <<= 1) {
#pragma unroll
        for (int mi = 0; mi < 2; mi++)
#pragma unroll
            for (int r = 0; r < 4; r++) {
                float os = __shfl_xor(best[mi][r], m);
                int   oi = __shfl_xor(bidx[mi][r], m);
                if (os < best[mi][r] || (os == best[mi][r] && oi < bidx[mi][r])) {
                    best[mi][r] = os; bidx[mi][r] = oi;
                }
            }
    }
    if (l15 == 0) {
        int g = lane >> 4;
#pragma unroll
        for (int mi = 0; mi < 2; mi++)
#pragma unroll
            for (int r = 0; r < 4; r++)
                ind[pos0 + wv * 32 + mi * 16 + g * 4 + r] = bidx[mi][r];
    }
}

// -------------- VQ gather -> Pq padded bf16 + loss partials ----------------
__global__ __launch_bounds__(256) void vq_gather_k(const float* __restrict__ zr,
        const float* __restrict__ cb, const int* __restrict__ ind,
        short* __restrict__ q, float* __restrict__ part) {
    int pos = blockIdx.x * 256 + threadIdx.x;
    int b = pos >> 10, hw = pos & 1023, y = hw >> 5, xx = hw & 31;
    int idx = ind[pos];
    const float4* cp = (const float4*)(cb + (size_t)idx * 64);
    const float4* zp = (const float4*)(zr + (size_t)pos * 64);
    size_t qb = (((size_t)b * 36 + y + 2) * 36 + xx + 2) * 64;
    float sum = 0.f;
#pragma unroll
    for (int d4 = 0; d4 < 16; d4++) {
        float4 c = cp[d4], z = zp[d4];
        float dx = c.x - z.x, dy = c.y - z.y, dz = c.z - z.z, dw = c.w - z.w;
        sum += dx * dx + dy * dy + dz * dz + dw * dw;
        ((int*)(q + qb))[2 * d4] = pack2(c.x, c.y);
        ((int*)(q + qb))[2 * d4 + 1] = pack2(c.z, c.w);
    }
#pragma unroll
    for (int m = 1; m < 64; m <<= 1) sum += __shfl_xor(sum, m);
    __shared__ float sred[4];
    int lane = threadIdx.x & 63, wvv = threadIdx.x >> 6;
    if (lane == 0) sred[wvv] = sum;
    __syncthreads();
    if (threadIdx.x == 0)
        part[blockIdx.x] = sred[0] + sred[1] + sred[2] + sred[3];
}

__global__ void finalize_k(const float* __restrict__ part, float* __restrict__ out) {
    if (threadIdx.x == 0) {
        float s = 0.f;
        for (int k = 0; k < 64; k++) s += part[k];
        float m = s / 1048576.f;
        out[786432] = m;
        out[786433] = m;
    }
}

// -------- tw1: ConvT 4x4 s2 p1, 128->3, input padded-68 bf16, tanh ---------
__global__ __launch_bounds__(256) void tw1_k(const short* __restrict__ in,
        const float* __restrict__ W, const float* __restrict__ bias,
        float* __restrict__ out) {
    __shared__ float sW[16 * 128 * 4];
    int b = blockIdx.y, y0 = blockIdx.x * 8;
    int tid = threadIdx.x;
    for (int t = tid; t < 2048; t += 256) {
        int k = t >> 7, ic = t & 127;
        float4 v;
        v.x = W[((size_t)ic * 3 + 0) * 16 + k];
        v.y = W[((size_t)ic * 3 + 1) * 16 + k];
        v.z = W[((size_t)ic * 3 + 2) * 16 + k];
        v.w = 0.f;
        *(float4*)&sW[t * 4] = v;
    }
    __syncthreads();
    int r = tid >> 5, g = tid & 31;
    int oy = y0 + r, py = oy & 1, Y = oy >> 1, pxp = g & 1;
    float acc[4][3];
#pragma unroll
    for (int p = 0; p < 4; p++)
#pragma unroll
        for (int o = 0; o < 3; o++) acc[p][o] = 0.f;
#pragma unroll
    for (int my = 0; my < 2; my++) {
        int iy = Y + ((py == 0) ? -my : 1 - my) + 2;
        const short* rowp = in + (((size_t)b * 68 + iy) * 68) * 128;
        int ky = 2 * my + (py ^ 1);
#pragma unroll
        for (int mx = 0; mx < 2; mx++) {
            int kx = 2 * mx + (pxp ^ 1);
            int cof = ((pxp == 0) ? -mx : 1 - mx) + 2;
            const float* wbase = &sW[((ky * 4 + kx) * 128) * 4];
            const short* pptr[4];
#pragma unroll
            for (int p = 0; p < 4; p++) {
                int X = ((g + 32 * p) >> 1) + cof;
                pptr[p] = rowp + (size_t)X * 128;
            }
            for (int icb = 0; icb < 16; icb++) {
                bf16x8 v[4];
#pragma unroll
                for (int p = 0; p < 4; p++)
                    v[p] = *(const bf16x8*)(pptr[p] + icb * 8);
#pragma unroll
                for (int j = 0; j < 8; j++) {
                    float4 w = *(const float4*)&wbase[(icb * 8 + j) * 4];
#pragma unroll
                    for (int p = 0; p < 4; p++) {
                        float xv = bf2f(v[p][j]);
                        acc[p][0] += w.x * xv;
                        acc[p][1] += w.y * xv;
                        acc[p][2] += w.z * xv;
                    }
                }
            }
        }
    }
#pragma unroll
    for (int p = 0; p < 4; p++) {
        int ox = g + 32 * p;
#pragma unroll
        for (int o = 0; o < 3; o++)
            out[(((size_t)b * 3 + o) << 14) + oy * 128 + ox] =
                tanhf(acc[p][o] + bias[o]);
    }
}

// ---------------------------------------------------------------------------
extern "C" void kernel_launch(void* const* d_in, const int* in_sizes, int n_in,
                              void* d_out, int out_size, void* d_ws, size_t ws_size,
                              hipStream_t stream) {
    const float* x    = (const float*)d_in[0];
    const float* ew0  = (const float*)d_in[1];
    const float* eb0  = (const float*)d_in[2];
    const float* ew1  = (const float*)d_in[3];
    const float* eb1  = (const float*)d_in[4];
    const float* ew2  = (const float*)d_in[5];
    const float* eb2  = (const float*)d_in[6];
    const float* erw3 = (const float*)d_in[7];
    const float* erw1 = (const float*)d_in[8];
    const float* ew3  = (const float*)d_in[9];
    const float* eb3  = (const float*)d_in[10];
    const float* cbk  = (const float*)d_in[11];
    const float* dw0  = (const float*)d_in[12];
    const float* db0  = (const float*)d_in[13];
    const float* drw3 = (const float*)d_in[14];
    const float* drw1 = (const float*)d_in[15];
    const float* tw0  = (const float*)d_in[16];
    const float* tb0  = (const float*)d_in[17];
    const float* tw1  = (const float*)d_in[18];
    const float* tb1  = (const float*)d_in[19];
    float* out = (float*)d_out;

    short* S = (short*)d_ws;
    short* P0  = S;                       // [16][68][68][128]
    short* PB  = P0 + 9469952;            // [16][36][36][256]
    short* PC  = PB + 5308416;
    short* Pq  = PC + 5308416;            // [16][36][36][64]
    short* Wp1 = Pq + 1327104;
    short* We2 = Wp1 + 524288;
    short* Wer3 = We2 + 589824;
    short* We11 = Wer3 + 3538944;
    short* Wz   = We11 + 393216;
    short* Wd0  = Wz + 16384;
    short* Wdr3 = Wd0 + 147456;
    short* Wdr1 = Wdr3 + 3538944;
    short* Wt0  = Wdr1 + 393216;
    float* F   = (float*)(S + 31080448);
    float* Zr  = F;                       // [16384][64]
    float* PART = Zr + 1048576;
    int*   IND = (int*)(PART + 64);

    halo_all_k<<<1752, 256, 0, stream>>>(P0, PB, PC, Pq);
    prep_all_k<<<3792, 256, 0, stream>>>(ew1, ew2, erw3, erw1, ew3, dw0,
        drw3, drw1, tw0, Wp1, We2, Wer3, We11, Wz, Wd0, Wdr3, Wdr1, Wt0);

    // ---------------- encoder ----------------
    conv0_k<<<dim3(64, 16), 256, 0, stream>>>(x, ew0, eb0, P0);
    rconv_k<128, 16, 2, 2, 68, 2, true, false>
        <<<256, 1024, 0, stream>>>(P0, Wp1, eb1, nullptr, PB);
    rconv_k<256, 9, 1, 1, 36, 2, true, false>
        <<<256, 1024, 0, stream>>>(PB, We2, eb2, nullptr, PC);
    for (int i = 0; i < 6; i++) {
        short* inb  = (i & 1) ? PB : PC;
        short* outb = (i & 1) ? PC : PB;
        if (i < 5)
            rconv_k<256, 9, 1, 1, 36, 0, false, true>
                <<<256, 1024, 0, stream>>>(inb, Wer3 + (size_t)i * 589824,
                    nullptr, We11 + (size_t)i * 65536, outb);
        else
            rconv_k<256, 9, 1, 1, 36, 2, false, true>
                <<<256, 1024, 0, stream>>>(inb, Wer3 + (size_t)i * 589824,
                    nullptr, We11 + (size_t)i * 65536, outb);
    }
    gconv_k<256, 64, 1, 0, 1, 36, 2, false, true, 1, 64>
        <<<dim3(128, 1), 256, 0, stream>>>(PC, Wz, eb3, nullptr, Zr);

    // ---------------- vector quantization ----------------
    vq_argmin_k<<<128, 256, 0, stream>>>(Zr, cbk, IND);
    vq_gather_k<<<64, 256, 0, stream>>>(Zr, cbk, IND, Pq, PART);

    // ---------------- decoder ----------------
    rconv_k<64, 9, 1, 1, 36, 2, true, false>
        <<<256, 1024, 0, stream>>>(Pq, Wd0, db0, nullptr, PC);
    for (int i = 0; i < 6; i++) {
        short* inb  = (i & 1) ? PB : PC;
        short* outb = (i & 1) ? PC : PB;
        if (i < 5)
            rconv_k<256, 9, 1, 1, 36, 0, false, true>
                <<<256, 1024, 0, stream>>>(inb, Wdr3 + (size_t)i * 589824,
                    nullptr, Wdr1 + (size_t)i * 65536, outb);
        else
            rconv_k<256, 9, 1, 1, 36, 2, false, true>
                <<<256, 1024, 0, stream>>>(inb, Wdr3 + (size_t)i * 589824,
                    nullptr, Wdr1 + (size_t)i * 65536, outb);
    }
    gconv_k<256, 128, 4, 3, 1, 36, 2, false, true, 2, 128>
        <<<dim3(128, 1, 4), 256, 0, stream>>>(PC, Wt0, tb0, nullptr, P0);
    tw1_k<<<dim3(16, 16), 256, 0, stream>>>(P0, tw1, tb1, out);

    finalize_k<<<1, 64, 0, stream>>>(PART, out);
}